// Round 1
// baseline (95.411 us; speedup 1.0000x reference)
//
#include <hip/hip_runtime.h>
#include <hip/hip_bf16.h>

// Problem: B=8192, D=256, INNER=64, OUT=256, fp32 in/out.
//   inner[b,d] = b2[d] + sum_i relu(x[b,d]*w1[d,i]+b1[d,i])*w2[d,i]
//   g[b,j]     = relu(sum_d inner[b,d]*wo1[j,d] + bo1[j])
//   out[b,o]   = sum_j g[b,j]*wo2[o,j] + bo2[o]
//
// R6: harness poison fills (2x41us, 256MiB ws) dominate dur; optimizable
// slice is prep+main (~8.5us). Changes vs R5:
//  - RB 16->32, NT 512->1024, grid 256 (1 block/CU): per-CU pa traffic
//    halved (4 threads/d share L1 lines), step A goes VALU-bound.
//  - prep shrunk 3x: only packs pa=(w1,b1,w2,0). Steps B/C load wo1/wo2
//    directly from global (float4 x2) + in-register fp32->bf16 cvt --
//    numerically identical to prepacked path.
//  - Step B uses 8 waves (2 Mtiles x 4 Ntiles), step C all 16 waves.

#define B_TOT 8192
#define D_DIM 256
#define I_DIM 64
#define O_DIM 256
#define RB 32          // batch rows per block
#define NT 1024        // threads per block

typedef __hip_bfloat16 bf16;
using short8 = __attribute__((ext_vector_type(8))) short;
using f32x4  = __attribute__((ext_vector_type(4))) float;

// d_ws layout:
//   pa : float4[64*256] @ byte 0 (256 KB): (w1[d][i], b1[d][i], w2[d][i], 0) at [i*256+d]

__global__ __launch_bounds__(256)
void kal_prep(const float* __restrict__ w1, const float* __restrict__ b1,
              const float* __restrict__ w2, float4* __restrict__ ws) {
    int idx = blockIdx.x * 256 + threadIdx.x;   // 0 .. 16383
    int i = idx >> 8;          // 0..63
    int d = idx & 255;         // 0..255
    ws[idx] = make_float4(w1[d * I_DIM + i], b1[d * I_DIM + i],
                          w2[d * I_DIM + i], 0.0f);
}

// fp32 -> bf16 raw bits (same rounding as __float2bfloat16 used on LDS path)
static __device__ __forceinline__ short f2bs(float f) {
    bf16 h = __float2bfloat16(f);
    return *reinterpret_cast<short*>(&h);
}

static __device__ __forceinline__ short8 cvt_frag(float4 a, float4 b) {
    short8 r;
    r[0] = f2bs(a.x); r[1] = f2bs(a.y); r[2] = f2bs(a.z); r[3] = f2bs(a.w);
    r[4] = f2bs(b.x); r[5] = f2bs(b.y); r[6] = f2bs(b.z); r[7] = f2bs(b.w);
    return r;
}

__global__ __launch_bounds__(NT)
void kal_main(const float* __restrict__ x,  const float* __restrict__ b2,
              const float* __restrict__ bo1, const float* __restrict__ bo2,
              const float* __restrict__ wo1, const float* __restrict__ wo2,
              const float4* __restrict__ pa, float* __restrict__ out) {
    __shared__ bf16 inner_bf[RB][264];   // +8 pad: b128 frag reads <=2-way bank alias
    __shared__ bf16 g_bf[RB][72];        // +8 pad

    const int t    = threadIdx.x;
    const int row0 = blockIdx.x * RB;

    // ---------------- Step A: per-feature inner MLPs (fp32 VALU) ------------
    {
        const int d = t & 255;
        const int q = t >> 8;             // 0..3 : quarter handles 8 rows
        float xv[8], acc[8];
        const float b2v = b2[d];
        #pragma unroll
        for (int b = 0; b < 8; ++b) {
            xv[b]  = x[(row0 + q * 8 + b) * D_DIM + d];   // coalesced
            acc[b] = b2v;
        }
        #pragma unroll 8
        for (int i = 0; i < I_DIM; ++i) {
            const float4 w = pa[i * D_DIM + d];   // one dwordx4: (w1,b1,w2,_)
            #pragma unroll
            for (int b = 0; b < 8; ++b) {
                float h = fmaf(xv[b], w.x, w.y);
                h = fmaxf(h, 0.0f);
                acc[b] = fmaf(h, w.z, acc[b]);
            }
        }
        #pragma unroll
        for (int b = 0; b < 8; ++b)
            inner_bf[q * 8 + b][d] = __float2bfloat16(acc[b]);
    }
    __syncthreads();

    const int lane = t & 63;
    const int wave = t >> 6;       // 0..15
    const int col  = lane & 15;    // MFMA m/n index
    const int quad = lane >> 4;    // MFMA k-group / row-group

    // ---------------- Step B: [32x256] @ wo1^T -> [32x64], MFMA -------------
    // 8 waves: 2 M-tiles x 4 N-tiles. wo1 loaded direct from global (L2-warm).
    if (wave < 8) {
        const int mt = wave >> 2;            // M-tile 0/1
        const int j0 = (wave & 3) * 16;      // N-tile
        const int jr = j0 + col;
        f32x4 acc = {0.f, 0.f, 0.f, 0.f};
        #pragma unroll
        for (int kc = 0; kc < 8; ++kc) {
            // A-frag: inner[m=mt*16+col][k=kc*32+quad*8 ..+7], 16B LDS read
            short8 af = *(const short8*)&inner_bf[mt * 16 + col][kc * 32 + quad * 8];
            // B-frag: wo1[jr][kc*32+quad*8 ..+7], two dwordx4 + cvt
            const float4* wp = (const float4*)&wo1[jr * D_DIM + kc * 32 + quad * 8];
            short8 bfr = cvt_frag(wp[0], wp[1]);
            acc = __builtin_amdgcn_mfma_f32_16x16x32_bf16(af, bfr, acc, 0, 0, 0);
        }
        const float bo1v = bo1[jr];
        #pragma unroll
        for (int r = 0; r < 4; ++r) {
            const int row = mt * 16 + quad * 4 + r;   // C/D: row=quad*4+reg, col=lane&15
            g_bf[row][jr] = __float2bfloat16(fmaxf(acc[r] + bo1v, 0.0f));
        }
    }
    __syncthreads();

    // ---------------- Step C: [32x64] @ wo2^T -> [32x256], MFMA -------------
    // 16 waves x 2 tiles = 2 M-tiles x 16 N-tiles.
    {
        const int mt = wave >> 3;            // M-tile 0/1
        const int jw = wave & 7;
        #pragma unroll
        for (int tt = 0; tt < 2; ++tt) {
            const int o0 = (jw * 2 + tt) * 16;
            const int oc = o0 + col;
            f32x4 acc = {0.f, 0.f, 0.f, 0.f};
            #pragma unroll
            for (int kc = 0; kc < 2; ++kc) {
                short8 af = *(const short8*)&g_bf[mt * 16 + col][kc * 32 + quad * 8];
                const float4* wp = (const float4*)&wo2[oc * I_DIM + kc * 32 + quad * 8];
                short8 bfr = cvt_frag(wp[0], wp[1]);
                acc = __builtin_amdgcn_mfma_f32_16x16x32_bf16(af, bfr, acc, 0, 0, 0);
            }
            const float bo2v = bo2[oc];
            #pragma unroll
            for (int r = 0; r < 4; ++r)
                out[(row0 + mt * 16 + quad * 4 + r) * O_DIM + oc] = acc[r] + bo2v;
        }
    }
}

extern "C" void kernel_launch(void* const* d_in, const int* in_sizes, int n_in,
                              void* d_out, int out_size, void* d_ws, size_t ws_size,
                              hipStream_t stream) {
    const float* x   = (const float*)d_in[0];
    const float* w1  = (const float*)d_in[1];
    const float* b1  = (const float*)d_in[2];
    const float* w2  = (const float*)d_in[3];
    const float* b2  = (const float*)d_in[4];
    const float* wo1 = (const float*)d_in[5];
    const float* bo1 = (const float*)d_in[6];
    const float* wo2 = (const float*)d_in[7];
    const float* bo2 = (const float*)d_in[8];
    float* out = (float*)d_out;
    float4* ws = (float4*)d_ws;

    kal_prep<<<64, 256, 0, stream>>>(w1, b1, w2, ws);
    kal_main<<<B_TOT / RB, NT, 0, stream>>>(x, b2, bo1, bo2, wo1, wo2, ws, out);
}

// Round 2
// 86.156 us; speedup vs baseline: 1.1074x; 1.1074x over previous
//
#include <hip/hip_runtime.h>
#include <hip/hip_bf16.h>

// Problem: B=8192, D=256, INNER=64, OUT=256, fp32 in/out.
//   inner[b,d] = b2[d] + sum_i relu(x[b,d]*w1[d,i]+b1[d,i])*w2[d,i]
//   g[b,j]     = relu(sum_d inner[b,d]*wo1[j,d] + bo1[j])
//   out[b,o]   = sum_j g[b,j]*wo2[o,j] + bo2[o]
//
// R7: revert to R5 structure (RB=16/NT=512/grid 512: 2 blocks/CU so barrier
// stalls overlap; prepacked coalesced wo1/wo2). New: step A in packed fp16 —
// per i-PAIR: v_pk_fma_f16 (h) + v_pk_max_f16 (relu) + v_dot2_f32_f16
// (fp32 accumulate) = 3 instr / 2 elems, halving the 5.1us VALU floor.
// Weights repacked as half2 (i,i+1) pairs: 6B/elem, 96KB total, coalesced
// dwordx4 loads (3 quads per 8-i group per d).

#define B_TOT 8192
#define D_DIM 256
#define I_DIM 64
#define O_DIM 256
#define RB 16          // batch rows per block
#define NT 512         // threads per block

typedef __hip_bfloat16 bf16;
using short8 = __attribute__((ext_vector_type(8))) short;
using f32x4  = __attribute__((ext_vector_type(4))) float;
using hlf2   = __attribute__((ext_vector_type(2))) _Float16;

// d_ws layout:
//   paq : uint4[8*3*256] @ 0       (96 KB)  fp16 inner-MLP weights, see below
//   pbB : bf16[8*64*32]  @ 98304   (32 KB)  pbB[(kc*64+j)*32+kk]  = wo1[j][kc*32+kk]
//   pcB : bf16[2*256*32] @ 131072  (32 KB)  pcB[(kc*256+o)*32+kk] = wo2[o][kc*32+kk]
//
// paq packing: for i-group g (8 i's = 4 pairs) and feature d, three uint4
// words at paq[(g*3+q)*256 + d]; each uint = half2(v[2k], v[2k+1]):
//   q0 = (w1p0, b1p0, w2p0, w1p1)
//   q1 = (b1p1, w2p1, w1p2, b1p2)
//   q2 = (w2p2, w1p3, b1p3, w2p3)

static __device__ __forceinline__ unsigned h2bits(float a, float b) {
    hlf2 v = { (_Float16)a, (_Float16)b };
    return __builtin_bit_cast(unsigned, v);
}
static __device__ __forceinline__ hlf2 bch2(unsigned u) {
    return __builtin_bit_cast(hlf2, u);
}

__global__ __launch_bounds__(256)
void kal_prep(const float* __restrict__ w1, const float* __restrict__ b1,
              const float* __restrict__ w2, const float* __restrict__ wo1,
              const float* __restrict__ wo2, uint4* __restrict__ ws) {
    int idx = blockIdx.x * 256 + threadIdx.x;   // 0 .. 34815
    if (idx < 2048) {
        // paq: thread per (g,d). Reads 32B contiguous per array per thread.
        int g = idx >> 8;          // 0..7
        int d = idx & 255;         // 0..255
        float v1[8], vb[8], v2[8];
        #pragma unroll
        for (int k = 0; k < 8; ++k) {
            v1[k] = w1[d * I_DIM + g * 8 + k];
            vb[k] = b1[d * I_DIM + g * 8 + k];
            v2[k] = w2[d * I_DIM + g * 8 + k];
        }
        unsigned w1p[4], b1p[4], w2p[4];
        #pragma unroll
        for (int k = 0; k < 4; ++k) {
            w1p[k] = h2bits(v1[2*k], v1[2*k+1]);
            b1p[k] = h2bits(vb[2*k], vb[2*k+1]);
            w2p[k] = h2bits(v2[2*k], v2[2*k+1]);
        }
        ws[(g*3+0)*256 + d] = make_uint4(w1p[0], b1p[0], w2p[0], w1p[1]);
        ws[(g*3+1)*256 + d] = make_uint4(b1p[1], w2p[1], w1p[2], b1p[2]);
        ws[(g*3+2)*256 + d] = make_uint4(w2p[2], w1p[3], b1p[3], w2p[3]);
    } else if (idx < 18432) {
        int r  = idx - 2048;       // 0..16383 : pbB
        int kc = r >> 11;          // 0..7
        int rem = r & 2047;
        int j  = rem >> 5;         // 0..63
        int kk = rem & 31;         // 0..31
        bf16* pbB = (bf16*)((char*)ws + 98304);
        pbB[r] = __float2bfloat16(wo1[j * D_DIM + kc * 32 + kk]);
    } else {
        int r  = idx - 18432;      // 0..16383 : pcB
        int kc = r >> 13;          // 0..1
        int rem = r & 8191;
        int o  = rem >> 5;         // 0..255
        int kk = rem & 31;         // 0..31
        bf16* pcB = (bf16*)((char*)ws + 131072);
        pcB[r] = __float2bfloat16(wo2[o * I_DIM + kc * 32 + kk]);
    }
}

__global__ __launch_bounds__(NT)
void kal_main(const float* __restrict__ x,  const float* __restrict__ b2,
              const float* __restrict__ bo1, const float* __restrict__ bo2,
              const uint4* __restrict__ ws, float* __restrict__ out) {
    const uint4* paq = ws;
    const bf16*  pbB = (const bf16*)((const char*)ws + 98304);
    const bf16*  pcB = (const bf16*)((const char*)ws + 131072);

    __shared__ bf16 inner_bf[RB][264];   // +8 pad: b128 frag reads <=2-way bank alias
    __shared__ bf16 g_bf[RB][72];        // +8 pad

    const int t    = threadIdx.x;
    const int row0 = blockIdx.x * RB;

    // ------------- Step A: per-feature inner MLPs (packed fp16 VALU) --------
    {
        const int d    = t & 255;
        const int half = t >> 8;          // waves 0-3: rows 0-7, waves 4-7: rows 8-15
        hlf2  xh[8];
        float acc[8];
        const float b2v = b2[d];
        #pragma unroll
        for (int b = 0; b < 8; ++b) {
            float xv = x[(row0 + half * 8 + b) * D_DIM + d];   // coalesced
            _Float16 xf = (_Float16)xv;
            xh[b]  = (hlf2){ xf, xf };
            acc[b] = b2v;
        }
        const uint4* pw = paq + d;
        const hlf2 hz = { (_Float16)0.0f, (_Float16)0.0f };
        #pragma unroll 2
        for (int g = 0; g < 8; ++g) {
            const uint4 q0 = pw[(g*3 + 0) * 256];   // coalesced dwordx4
            const uint4 q1 = pw[(g*3 + 1) * 256];
            const uint4 q2 = pw[(g*3 + 2) * 256];
            const hlf2 w1p[4] = { bch2(q0.x), bch2(q0.w), bch2(q1.z), bch2(q2.y) };
            const hlf2 b1p[4] = { bch2(q0.y), bch2(q1.x), bch2(q1.w), bch2(q2.z) };
            const hlf2 w2p[4] = { bch2(q0.z), bch2(q1.y), bch2(q2.x), bch2(q2.w) };
            #pragma unroll
            for (int k = 0; k < 4; ++k) {
                #pragma unroll
                for (int b = 0; b < 8; ++b) {
                    hlf2 h = __builtin_elementwise_fma(xh[b], w1p[k], b1p[k]); // v_pk_fma_f16
                    h = __builtin_elementwise_max(h, hz);                      // v_pk_max_f16
                    acc[b] = __builtin_amdgcn_fdot2(h, w2p[k], acc[b], false); // v_dot2_f32_f16
                }
            }
        }
        #pragma unroll
        for (int b = 0; b < 8; ++b)
            inner_bf[half * 8 + b][d] = __float2bfloat16(acc[b]);
    }
    __syncthreads();

    const int lane = t & 63;
    const int wave = t >> 6;
    const int col  = lane & 15;    // MFMA m/n index
    const int quad = lane >> 4;    // MFMA k-group / row-group

    // ---------------- Step B: [16x256] @ wo1^T -> [16x64], MFMA -------------
    if (wave < 4) {
        const int j0 = wave * 16;            // N-tile
        f32x4 acc = {0.f, 0.f, 0.f, 0.f};
        #pragma unroll
        for (int kc = 0; kc < 8; ++kc) {
            // A-frag: inner[m=col][k=kc*32+quad*8 ..+7], 16B LDS read
            short8 af = *(const short8*)&inner_bf[col][kc * 32 + quad * 8];
            // B-frag: wo1 pre-packed, coalesced dwordx4
            short8 bfr = *(const short8*)&pbB[(kc * 64 + j0 + col) * 32 + quad * 8];
            acc = __builtin_amdgcn_mfma_f32_16x16x32_bf16(af, bfr, acc, 0, 0, 0);
        }
        const float bo1v = bo1[j0 + col];
        #pragma unroll
        for (int r = 0; r < 4; ++r) {
            const int row = quad * 4 + r;    // C/D: row = quad*4+reg, col = lane&15
            g_bf[row][j0 + col] = __float2bfloat16(fmaxf(acc[r] + bo1v, 0.0f));
        }
    }
    __syncthreads();

    // ---------------- Step C: [16x64] @ wo2^T -> [16x256], MFMA -------------
    #pragma unroll
    for (int tile = 0; tile < 2; ++tile) {
        const int o0 = wave * 16 + tile * 128;   // 8 waves x 2 tiles = 16 N-tiles
        f32x4 acc = {0.f, 0.f, 0.f, 0.f};
        #pragma unroll
        for (int kc = 0; kc < 2; ++kc) {
            short8 af = *(const short8*)&g_bf[col][kc * 32 + quad * 8];
            short8 bfr = *(const short8*)&pcB[(kc * 256 + o0 + col) * 32 + quad * 8];
            acc = __builtin_amdgcn_mfma_f32_16x16x32_bf16(af, bfr, acc, 0, 0, 0);
        }
        const float bo2v = bo2[o0 + col];
        #pragma unroll
        for (int r = 0; r < 4; ++r)
            out[(row0 + quad * 4 + r) * O_DIM + o0 + col] = acc[r] + bo2v;
    }
}

extern "C" void kernel_launch(void* const* d_in, const int* in_sizes, int n_in,
                              void* d_out, int out_size, void* d_ws, size_t ws_size,
                              hipStream_t stream) {
    const float* x   = (const float*)d_in[0];
    const float* w1  = (const float*)d_in[1];
    const float* b1  = (const float*)d_in[2];
    const float* w2  = (const float*)d_in[3];
    const float* b2  = (const float*)d_in[4];
    const float* wo1 = (const float*)d_in[5];
    const float* bo1 = (const float*)d_in[6];
    const float* wo2 = (const float*)d_in[7];
    const float* bo2 = (const float*)d_in[8];
    float* out = (float*)d_out;
    uint4* ws = (uint4*)d_ws;

    kal_prep<<<136, 256, 0, stream>>>(w1, b1, w2, wo1, wo2, ws);
    kal_main<<<B_TOT / RB, NT, 0, stream>>>(x, b2, bo1, bo2, ws, out);
}